// Round 1
// baseline (354.915 us; speedup 1.0000x reference)
//
#include <hip/hip_runtime.h>

#define TPB 512
#define FN  8192   // complex FFT size

// LDS physical swizzle (float2 units): b1^=b6, b2^=b7, b3^=b5.
// Bijective (modified bits only depend on untouched higher bits); keeps
// every radix-4 stage (strides 2048..2) at <=4 lanes per bank-pair for b64,
// and preserves adjacency of even/odd pairs (b0 untouched) for b128 access.
__device__ __forceinline__ int phys(int p) {
  return p ^ ((p >> 2) & 8) ^ ((p >> 5) & 6);
}

// Forward radix-4 DIF stages: s = 2048,512,128,32,8,2 (natural in, digit-reversed out)
__device__ __forceinline__ void fft_fwd_r4(float2* A, int tid) {
#pragma unroll 1
  for (int si = 0; si < 6; ++si) {
    const int lg = 11 - 2 * si;
    const int s = 1 << lg;
    const float tws = -1.5707963267948966f / (float)s;  // -pi/2 / s
    __syncthreads();
#pragma unroll
    for (int m = 0; m < 4; ++m) {
      const int j = tid + TPB * m;
      const int np = j & (s - 1);
      const int base = ((j >> lg) << (lg + 2)) | np;
      float2 a = A[phys(base)];
      float2 b = A[phys(base + s)];
      float2 c = A[phys(base + 2 * s)];
      float2 d = A[phys(base + 3 * s)];
      float t0r = a.x + c.x, t0i = a.y + c.y;
      float t1r = a.x - c.x, t1i = a.y - c.y;
      float t2r = b.x + d.x, t2i = b.y + d.y;
      float t3r = b.x - d.x, t3i = b.y - d.y;
      float u0r = t0r + t2r, u0i = t0i + t2i;
      float u2r = t0r - t2r, u2i = t0i - t2i;
      float u1r = t1r + t3i, u1i = t1i - t3r;   // (a-c) - i(b-d)
      float u3r = t1r - t3i, u3i = t1i + t3r;   // (a-c) + i(b-d)
      float ang = tws * (float)np;
      float s1, c1;
      __sincosf(ang, &s1, &c1);
      float c2 = c1 * c1 - s1 * s1, s2 = 2.f * c1 * s1;
      float c3 = c1 * c2 - s1 * s2, s3 = c1 * s2 + s1 * c2;
      A[phys(base)]         = make_float2(u0r, u0i);
      A[phys(base + s)]     = make_float2(u1r * c1 - u1i * s1, u1r * s1 + u1i * c1);
      A[phys(base + 2 * s)] = make_float2(u2r * c2 - u2i * s2, u2r * s2 + u2i * c2);
      A[phys(base + 3 * s)] = make_float2(u3r * c3 - u3i * s3, u3r * s3 + u3i * c3);
    }
  }
}

// Inverse radix-4 DIT stages: s = 2,8,32,128,512,2048. Exact (unscaled, x4 per
// stage) inverse of fft_fwd_r4; total growth 4^6*2 = 8192 folded into Hhat.
__device__ __forceinline__ void fft_inv_r4(float2* A, int tid) {
#pragma unroll 1
  for (int si = 0; si < 6; ++si) {
    const int lg = 1 + 2 * si;
    const int s = 1 << lg;
    const float tws = 1.5707963267948966f / (float)s;   // +pi/2 / s (conj twiddles)
    __syncthreads();
#pragma unroll
    for (int m = 0; m < 4; ++m) {
      const int j = tid + TPB * m;
      const int np = j & (s - 1);
      const int base = ((j >> lg) << (lg + 2)) | np;
      float2 v0 = A[phys(base)];
      float2 u1 = A[phys(base + s)];
      float2 u2 = A[phys(base + 2 * s)];
      float2 u3 = A[phys(base + 3 * s)];
      float ang = tws * (float)np;
      float s1, c1;
      __sincosf(ang, &s1, &c1);
      float c2 = c1 * c1 - s1 * s1, s2 = 2.f * c1 * s1;
      float c3 = c1 * c2 - s1 * s2, s3 = c1 * s2 + s1 * c2;
      float v1r = u1.x * c1 - u1.y * s1, v1i = u1.x * s1 + u1.y * c1;
      float v2r = u2.x * c2 - u2.y * s2, v2i = u2.x * s2 + u2.y * c2;
      float v3r = u3.x * c3 - u3.y * s3, v3i = u3.x * s3 + u3.y * c3;
      float x0r = v0.x + v1r + v2r + v3r, x0i = v0.y + v1i + v2i + v3i;
      float x2r = v0.x - v1r + v2r - v3r, x2i = v0.y - v1i + v2i - v3i;
      float x1r = v0.x - v1i - v2r + v3i, x1i = v0.y + v1r - v2i - v3r;  // +i*v1 - v2 - i*v3
      float x3r = v0.x + v1i - v2r - v3i, x3i = v0.y - v1r - v2i + v3r;  // -i*v1 - v2 + i*v3
      A[phys(base)]         = make_float2(x0r, x0i);
      A[phys(base + s)]     = make_float2(x1r, x1i);
      A[phys(base + 2 * s)] = make_float2(x2r, x2i);
      A[phys(base + 3 * s)] = make_float2(x3r, x3i);
    }
  }
}

// Precompute Hhat[2f+half][p] = DIF_scrambled_FFT8192(h[f, half*4096 : +4096] zero-padded)/8192
__global__ __launch_bounds__(TPB, 4) void h_fft(const float* __restrict__ h,
                                                float2* __restrict__ Hbuf) {
  __shared__ __align__(16) float2 A[FN];
  const int tid = threadIdx.x;
  const int q = blockIdx.x;                       // q = 2*f + half
  const float* hrow = h + (size_t)(q >> 1) * 8192 + (size_t)(q & 1) * 4096;
#pragma unroll
  for (int m = 0; m < 8; ++m) {
    int n = tid + TPB * m;                        // n in [0,4096)
    A[phys(n)] = make_float2(hrow[n], 0.f);
    A[phys(n + 4096)] = make_float2(0.f, 0.f);
  }
  fft_fwd_r4(A, tid);
  __syncthreads();
  float2* orow = Hbuf + (size_t)q * FN;
  const float sc = 1.f / 8192.f;
#pragma unroll
  for (int m = 0; m < 8; ++m) {
    int p = 2 * (tid + TPB * m);
    float4 za = *(const float4*)(&A[phys(p)]);    // final radix-2 in regs
    float4 st = make_float4((za.x + za.z) * sc, (za.y + za.w) * sc,
                            (za.x - za.z) * sc, (za.y - za.w) * sc);
    *(float4*)(&orow[p]) = st;
  }
}

// u (8,8192,256) -> xT (2048, 8192): xT[b*256+d][l] = u[b][l][d]
__global__ void transpose_in(const float* __restrict__ u, float* __restrict__ xT) {
  __shared__ float tile[64][65];
  const int l0 = blockIdx.x * 64, d0 = blockIdx.y * 64, b = blockIdx.z;
  const int tid = threadIdx.x;
#pragma unroll
  for (int k = 0; k < 16; ++k) {
    int idx = tid + 256 * k;
    int li = idx >> 6, di = idx & 63;
    tile[li][di] = u[(size_t)(b * 8192 + l0 + li) * 256 + d0 + di];
  }
  __syncthreads();
#pragma unroll
  for (int k = 0; k < 16; ++k) {
    int idx = tid + 256 * k;
    int ri = idx >> 6, ci = idx & 63;
    xT[(size_t)(b * 256 + d0 + ri) * 8192 + l0 + ci] = tile[ci][ri];
  }
}

// yT (2048, 8192) -> out (8,8192,256): out[b][l][d] = yT[b*256+d][l]
__global__ void transpose_out(const float* __restrict__ yT, float* __restrict__ out) {
  __shared__ float tile[64][65];
  const int l0 = blockIdx.x * 64, d0 = blockIdx.y * 64, b = blockIdx.z;
  const int tid = threadIdx.x;
#pragma unroll
  for (int k = 0; k < 16; ++k) {
    int idx = tid + 256 * k;
    int ri = idx >> 6, ci = idx & 63;
    tile[ci][ri] = yT[(size_t)(b * 256 + d0 + ri) * 8192 + l0 + ci];
  }
  __syncthreads();
#pragma unroll
  for (int k = 0; k < 16; ++k) {
    int idx = tid + 256 * k;
    int li = idx >> 6, di = idx & 63;
    out[(size_t)(b * 8192 + l0 + li) * 256 + d0 + di] = tile[li][di];
  }
}

// One row per block: z = x0 + i*x1 (4096 each, zero-padded to 8192), fwd FFT,
// for each filter half j: W = Z*Hhat_j, inv FFT, gather shifted taps:
// y[l] = Re w0[l+4095] + Im w0[l-1] + Re w1[l-1] + Im w1[l-4097]
__global__ __launch_bounds__(TPB, 4) void conv_main(const float* __restrict__ xT,
                                                    const float2* __restrict__ Hbuf,
                                                    float* __restrict__ yT) {
  __shared__ __align__(16) float2 A[FN];
  const int tid = threadIdx.x;
  const int r = blockIdx.x;
  const int f = r >> 3;                           // row_filter = r // B, B=8
  const float* xrow = xT + (size_t)r * 8192;
#pragma unroll
  for (int m = 0; m < 8; ++m) {
    int n = tid + TPB * m;                        // n in [0,4096)
    A[phys(n)] = make_float2(xrow[n], xrow[n + 4096]);
    A[phys(n + 4096)] = make_float2(0.f, 0.f);
  }
  fft_fwd_r4(A, tid);
  __syncthreads();
  // final forward radix-2 (pairs 2t,2t+1) kept in registers
  float Zr[16], Zi[16];
#pragma unroll
  for (int m = 0; m < 8; ++m) {
    int ph = phys(2 * (tid + TPB * m));
    float4 za = *(const float4*)(&A[ph]);
    Zr[2 * m]     = za.x + za.z;  Zi[2 * m]     = za.y + za.w;
    Zr[2 * m + 1] = za.x - za.z;  Zi[2 * m + 1] = za.y - za.w;
  }
  const float2* H0 = Hbuf + (size_t)(2 * f) * FN;
  const float2* H1 = H0 + FN;
  float p0[16];
  // ---------- half 0: W = Z*H0, undo radix-2, inverse ----------
#pragma unroll
  for (int m = 0; m < 8; ++m) {
    int p = 2 * (tid + TPB * m);
    float4 hv = *(const float4*)(&H0[p]);
    float w0r = Zr[2*m] * hv.x - Zi[2*m] * hv.y;
    float w0i = Zr[2*m] * hv.y + Zi[2*m] * hv.x;
    float w1r = Zr[2*m+1] * hv.z - Zi[2*m+1] * hv.w;
    float w1i = Zr[2*m+1] * hv.w + Zi[2*m+1] * hv.z;
    *(float4*)(&A[phys(p)]) = make_float4(w0r + w1r, w0i + w1i, w0r - w1r, w0i - w1i);
  }
  fft_inv_r4(A, tid);
  __syncthreads();
#pragma unroll
  for (int m = 0; m < 16; ++m) {
    int l = tid + TPB * m;
    float acc = 0.f;
    if (l <= 4096) acc += A[phys(l + 4095)].x;    // (x0*h0)[l+4095]
    if (l >= 1)    acc += A[phys(l - 1)].y;       // (x1*h0)[l-1]
    p0[m] = acc;
  }
  __syncthreads();                                 // p0 reads done before overwrite
  // ---------- half 1 ----------
#pragma unroll
  for (int m = 0; m < 8; ++m) {
    int p = 2 * (tid + TPB * m);
    float4 hv = *(const float4*)(&H1[p]);
    float w0r = Zr[2*m] * hv.x - Zi[2*m] * hv.y;
    float w0i = Zr[2*m] * hv.y + Zi[2*m] * hv.x;
    float w1r = Zr[2*m+1] * hv.z - Zi[2*m+1] * hv.w;
    float w1i = Zr[2*m+1] * hv.w + Zi[2*m+1] * hv.z;
    *(float4*)(&A[phys(p)]) = make_float4(w0r + w1r, w0i + w1i, w0r - w1r, w0i - w1i);
  }
  fft_inv_r4(A, tid);
  __syncthreads();
  float* yrow = yT + (size_t)r * 8192;
#pragma unroll
  for (int m = 0; m < 16; ++m) {
    int l = tid + TPB * m;
    float acc = p0[m];
    if (l >= 1)    acc += A[phys(l - 1)].x;        // (x0*h1)[l-1]
    if (l >= 4097) acc += A[phys(l - 4097)].y;     // (x1*h1)[l-4097]
    yrow[l] = acc;
  }
}

extern "C" void kernel_launch(void* const* d_in, const int* in_sizes, int n_in,
                              void* d_out, int out_size, void* d_ws, size_t ws_size,
                              hipStream_t stream) {
  (void)in_sizes; (void)n_in; (void)out_size; (void)ws_size;
  const float* u = (const float*)d_in[0];   // (8, 8192, 256) f32
  const float* h = (const float*)d_in[1];   // (256, 8192) f32
  float* out = (float*)d_out;               // (8, 8192, 256) f32
  // workspace: [xT/yT: 2048*8192 f32 = 64 MB][Hhat: 512*8192 float2 = 32 MB]
  float* xT = (float*)d_ws;
  float2* Hbuf = (float2*)((char*)d_ws + (size_t)2048 * 8192 * 4);

  h_fft<<<512, TPB, 0, stream>>>(h, Hbuf);
  transpose_in<<<dim3(128, 4, 8), 256, 0, stream>>>(u, xT);
  conv_main<<<2048, TPB, 0, stream>>>(xT, Hbuf, xT);   // yT aliases xT (row-local)
  transpose_out<<<dim3(128, 4, 8), 256, 0, stream>>>(xT, out);
}